// Round 2
// baseline (748.710 us; speedup 1.0000x reference)
//
#include <hip/hip_runtime.h>
#include <stdint.h>

typedef _Float16 f16;
typedef _Float16 f16x8 __attribute__((ext_vector_type(8)));
typedef float f32x4 __attribute__((ext_vector_type(4)));

union U4 { uint4 u; f16 h[8]; };

// ---------------- weight transpose + cvt: Wt[n][k] = (f16)W[k][n], 1024x1024 fp32 in --
__global__ __launch_bounds__(256) void k_wt(const float* __restrict__ W,
                                            f16* __restrict__ Wt) {
    __shared__ f16 tile[64 * 65];
    int t = threadIdx.x;
    int k0 = blockIdx.x * 64, n0 = blockIdx.y * 64;
    #pragma unroll
    for (int i = 0; i < 4; i++) {
        int cid = t + i * 256;           // 1024 chunks of 4 floats
        int row = cid >> 4, c4 = cid & 15;
        float4 v = *(const float4*)(W + (size_t)(k0 + row) * 1024 + n0 + c4 * 4);
        tile[(c4 * 4 + 0) * 65 + row] = (f16)v.x;
        tile[(c4 * 4 + 1) * 65 + row] = (f16)v.y;
        tile[(c4 * 4 + 2) * 65 + row] = (f16)v.z;
        tile[(c4 * 4 + 3) * 65 + row] = (f16)v.w;
    }
    __syncthreads();
    #pragma unroll
    for (int i = 0; i < 2; i++) {
        int cid = t + i * 256;
        int nr = cid >> 3, kc = cid & 7;
        U4 u;
        #pragma unroll
        for (int j = 0; j < 8; j++) u.h[j] = tile[nr * 65 + kc * 8 + j];
        *(uint4*)(Wt + (size_t)(n0 + nr) * 1024 + k0 + kc * 8) = u.u;
    }
}

// ---------------- fp32 -> f16 elementwise ---------------------------------------------
__global__ __launch_bounds__(256) void k_cvt(const float* __restrict__ in,
                                             f16* __restrict__ out) {
    size_t id = (size_t)blockIdx.x * 256 + threadIdx.x;  // one 8-elem chunk
    float4 a = *(const float4*)(in + id * 8);
    float4 b = *(const float4*)(in + id * 8 + 4);
    U4 u;
    u.h[0] = (f16)a.x; u.h[1] = (f16)a.y; u.h[2] = (f16)a.z; u.h[3] = (f16)a.w;
    u.h[4] = (f16)b.x; u.h[5] = (f16)b.y; u.h[6] = (f16)b.z; u.h[7] = (f16)b.w;
    *(uint4*)(out + id * 8) = u.u;
}

// ---------------- mask: M from pc blocks, then 1->50->1 MLP, all fp32 ------------------
__global__ __launch_bounds__(256) void k_mask(const float* __restrict__ pc,
                                              const float* __restrict__ mw1,
                                              const float* __restrict__ mb1,
                                              const float* __restrict__ mw2,
                                              const float* __restrict__ mb2,
                                              float* __restrict__ maskp) {
    __shared__ float w1[50], b1[50], w2[50];
    int t = threadIdx.x;
    if (t < 50) { w1[t] = mw1[t]; b1[t] = mb1[t]; w2[t] = mw2[t]; }
    __syncthreads();
    int id = blockIdx.x * 256 + t;
    int i = id / 768, j = id - i * 768;
    float M;
    if (i < 512) {
        if (j < 512) {
            float s = 0.f;
            for (int u = 0; u < 256; u++) s += pc[u * 512 + i] * pc[u * 512 + j];
            M = s;
        } else {
            M = pc[(j - 512) * 512 + i];
        }
    } else {
        if (j < 512) {
            M = pc[(i - 512) * 512 + j];
        } else {
            float s = 0.f;
            const float* ra = pc + (i - 512) * 512;
            const float* rb = pc + (j - 512) * 512;
            for (int u = 0; u < 512; u++) s += ra[u] * rb[u];
            M = s;
        }
    }
    float acc = mb2[0];
    #pragma unroll 10
    for (int u = 0; u < 50; u++) acc += fmaxf(M * w1[u] + b1[u], 0.f) * w2[u];
    maskp[id] = acc;
}

// ---------------- GEMM: C = A(12288x1024) @ W(1024x1024) + bias ------------------------
// Bt is W transposed: Bt[n][k]. MODE 0: f16 out. MODE 1: f16 hi/lo split. MODE 2: fp32.
template <int MODE>
__global__ __launch_bounds__(256) void k_gemm(const f16* __restrict__ A,
                                              const f16* __restrict__ Bt,
                                              const float* __restrict__ bias,
                                              void* out0v, void* out1v) {
    __shared__ f16 As[128 * 40];
    __shared__ f16 Bs[128 * 40];
    int t = threadIdx.x;
    int w = t >> 6, lane = t & 63, l15 = lane & 15, quad = lane >> 4;
    int wm = w >> 1, wn = w & 1;
    int row0 = blockIdx.x * 128, n0 = blockIdx.y * 128;
    f32x4 acc[4][4];
    #pragma unroll
    for (int mi = 0; mi < 4; mi++)
        #pragma unroll
        for (int ni = 0; ni < 4; ni++) acc[mi][ni] = (f32x4){0.f, 0.f, 0.f, 0.f};

    for (int kt = 0; kt < 32; kt++) {
        int k0 = kt * 32;
        #pragma unroll
        for (int i = 0; i < 2; i++) {
            int cid = t + i * 256;
            int m = cid >> 2, kc = cid & 3;
            *(uint4*)&As[m * 40 + kc * 8] =
                *(const uint4*)(A + (size_t)(row0 + m) * 1024 + k0 + kc * 8);
            *(uint4*)&Bs[m * 40 + kc * 8] =
                *(const uint4*)(Bt + (size_t)(n0 + m) * 1024 + k0 + kc * 8);
        }
        __syncthreads();
        f16x8 af[4], bf_[4];
        #pragma unroll
        for (int mi = 0; mi < 4; mi++)
            af[mi] = *(const f16x8*)&As[(wm * 64 + mi * 16 + l15) * 40 + quad * 8];
        #pragma unroll
        for (int ni = 0; ni < 4; ni++)
            bf_[ni] = *(const f16x8*)&Bs[(wn * 64 + ni * 16 + l15) * 40 + quad * 8];
        #pragma unroll
        for (int mi = 0; mi < 4; mi++)
            #pragma unroll
            for (int ni = 0; ni < 4; ni++)
                acc[mi][ni] = __builtin_amdgcn_mfma_f32_16x16x32_f16(af[mi], bf_[ni],
                                                                     acc[mi][ni], 0, 0, 0);
        __syncthreads();
    }
    #pragma unroll
    for (int mi = 0; mi < 4; mi++) {
        #pragma unroll
        for (int ni = 0; ni < 4; ni++) {
            int col = n0 + wn * 64 + ni * 16 + l15;
            float bv = bias[col];
            #pragma unroll
            for (int r = 0; r < 4; r++) {
                int row = row0 + wm * 64 + mi * 16 + quad * 4 + r;
                float v = acc[mi][ni][r] + bv;
                size_t idx = (size_t)row * 1024 + col;
                if (MODE == 0) {
                    ((f16*)out0v)[idx] = (f16)v;
                } else if (MODE == 1) {
                    f16 hi = (f16)v;
                    ((f16*)out0v)[idx] = hi;
                    ((f16*)out1v)[idx] = (f16)(v - (float)hi);
                } else {
                    ((float*)out0v)[idx] = v;
                }
            }
        }
    }
}

// ---------------- flash attention, split-f16 QK, f16 PV --------------------------------
__global__ __launch_bounds__(256) void k_attn(const f16* __restrict__ Qhi,
                                              const f16* __restrict__ Qlo,
                                              const f16* __restrict__ Khi,
                                              const f16* __restrict__ Klo,
                                              const f16* __restrict__ Vh,
                                              const float* __restrict__ maskp,
                                              f16* __restrict__ Xout) {
    __shared__ f16 Ksh[32 * 72];
    __shared__ f16 Ksl[32 * 72];
    __shared__ f16 Vt[64 * 40];      // Vt[d][s]
    __shared__ f16 Ps[4][16 * 40];   // per-wave P in A-layout
    int t = threadIdx.x;
    int w = t >> 6, lane = t & 63, l15 = lane & 15, quad = lane >> 4;
    int q0 = blockIdx.x * 64;
    int bh = blockIdx.y; int b = bh >> 4, h = bh & 15;
    const size_t base = ((size_t)b * 768) * 1024 + h * 64;

    f16x8 qh[2], ql[2];
    int qrow = q0 + w * 16 + l15;
    #pragma unroll
    for (int c = 0; c < 2; c++) {
        qh[c] = *(const f16x8*)(Qhi + base + (size_t)qrow * 1024 + c * 32 + quad * 8);
        ql[c] = *(const f16x8*)(Qlo + base + (size_t)qrow * 1024 + c * 32 + quad * 8);
    }
    float mst[4], lst[4];
    f32x4 o[4];
    #pragma unroll
    for (int r = 0; r < 4; r++) { mst[r] = -1e30f; lst[r] = 0.f; }
    #pragma unroll
    for (int ni = 0; ni < 4; ni++) o[ni] = (f32x4){0.f, 0.f, 0.f, 0.f};

    for (int kt = 0; kt < 24; kt++) {
        int k0 = kt * 32;
        __syncthreads();
        {   // stage K hi/lo tiles and transposed V tile
            int row = t >> 3, dc = t & 7;
            *(uint4*)&Ksh[row * 72 + dc * 8] =
                *(const uint4*)(Khi + base + (size_t)(k0 + row) * 1024 + dc * 8);
            *(uint4*)&Ksl[row * 72 + dc * 8] =
                *(const uint4*)(Klo + base + (size_t)(k0 + row) * 1024 + dc * 8);
            U4 u; u.u = *(const uint4*)(Vh + base + (size_t)(k0 + row) * 1024 + dc * 8);
            #pragma unroll
            for (int j = 0; j < 8; j++) Vt[(dc * 8 + j) * 40 + row] = u.h[j];
        }
        __syncthreads();

        float sv[2][4];
        #pragma unroll
        for (int kn = 0; kn < 2; kn++) {
            f32x4 s = (f32x4){0.f, 0.f, 0.f, 0.f};
            int key = kn * 16 + l15;
            #pragma unroll
            for (int c = 0; c < 2; c++) {
                f16x8 kh = *(const f16x8*)&Ksh[key * 72 + c * 32 + quad * 8];
                f16x8 kl = *(const f16x8*)&Ksl[key * 72 + c * 32 + quad * 8];
                s = __builtin_amdgcn_mfma_f32_16x16x32_f16(qh[c], kh, s, 0, 0, 0);
                s = __builtin_amdgcn_mfma_f32_16x16x32_f16(ql[c], kh, s, 0, 0, 0);
                s = __builtin_amdgcn_mfma_f32_16x16x32_f16(qh[c], kl, s, 0, 0, 0);
            }
            #pragma unroll
            for (int r = 0; r < 4; r++) {
                float mv = maskp[(q0 + w * 16 + quad * 4 + r) * 768 + k0 + kn * 16 + l15];
                sv[kn][r] = s[r] * 0.125f * mv;
            }
        }
        // online softmax (rows live in quads; reduce across the 16 lanes of each quad)
        #pragma unroll
        for (int r = 0; r < 4; r++) {
            float tm = fmaxf(sv[0][r], sv[1][r]);
            tm = fmaxf(tm, __shfl_xor(tm, 1));
            tm = fmaxf(tm, __shfl_xor(tm, 2));
            tm = fmaxf(tm, __shfl_xor(tm, 4));
            tm = fmaxf(tm, __shfl_xor(tm, 8));
            float mn = fmaxf(mst[r], tm);
            float alpha = __expf(mst[r] - mn);
            mst[r] = mn;
            float p0 = __expf(sv[0][r] - mn), p1 = __expf(sv[1][r] - mn);
            float rs = p0 + p1;
            rs += __shfl_xor(rs, 1);
            rs += __shfl_xor(rs, 2);
            rs += __shfl_xor(rs, 4);
            rs += __shfl_xor(rs, 8);
            lst[r] = lst[r] * alpha + rs;
            #pragma unroll
            for (int ni = 0; ni < 4; ni++) o[ni][r] *= alpha;
            Ps[w][(quad * 4 + r) * 40 + l15] = (f16)p0;
            Ps[w][(quad * 4 + r) * 40 + 16 + l15] = (f16)p1;
        }
        asm volatile("s_waitcnt lgkmcnt(0)" ::: "memory");  // P write -> A-frag read (same wave)
        f16x8 pa = *(const f16x8*)&Ps[w][l15 * 40 + quad * 8];
        #pragma unroll
        for (int ni = 0; ni < 4; ni++) {
            f16x8 vb = *(const f16x8*)&Vt[(ni * 16 + l15) * 40 + quad * 8];
            o[ni] = __builtin_amdgcn_mfma_f32_16x16x32_f16(pa, vb, o[ni], 0, 0, 0);
        }
    }
    #pragma unroll
    for (int ni = 0; ni < 4; ni++)
        #pragma unroll
        for (int r = 0; r < 4; r++) {
            int row = q0 + w * 16 + quad * 4 + r;
            int col = ni * 16 + l15;
            Xout[((size_t)b * 768 + row) * 1024 + h * 64 + col] = (f16)(o[ni][r] / lst[r]);
        }
}

// ---------------- launch ---------------------------------------------------------------
extern "C" void kernel_launch(void* const* d_in, const int* in_sizes, int n_in,
                              void* d_out, int out_size, void* d_ws, size_t ws_size,
                              hipStream_t stream) {
    (void)in_sizes; (void)n_in; (void)out_size; (void)ws_size;
    const float* query = (const float*)d_in[0];
    const float* key   = (const float*)d_in[1];
    const float* value = (const float*)d_in[2];
    const float* pc    = (const float*)d_in[3];
    const float* Wq    = (const float*)d_in[4];
    const float* bq    = (const float*)d_in[5];
    const float* Wk    = (const float*)d_in[6];
    const float* bk    = (const float*)d_in[7];
    const float* Wv    = (const float*)d_in[8];
    const float* bv    = (const float*)d_in[9];
    const float* Wo    = (const float*)d_in[10];
    const float* bo    = (const float*)d_in[11];
    const float* mw1   = (const float*)d_in[12];
    const float* mb1   = (const float*)d_in[13];
    const float* mw2   = (const float*)d_in[14];
    const float* mb2   = (const float*)d_in[15];

    char* p = (char*)d_ws;
    auto take = [&](size_t bytes) -> char* {
        char* r = p; p += (bytes + 255) & ~(size_t)255; return r;
    };
    const size_t NTOK = 12288, DM = 1024;
    float* maskb = (float*)take(768 * 768 * 4);
    f16* Wqt = (f16*)take(DM * DM * 2);
    f16* Wkt = (f16*)take(DM * DM * 2);
    f16* Wvt = (f16*)take(DM * DM * 2);
    f16* Wot = (f16*)take(DM * DM * 2);
    f16* buf1 = (f16*)take(NTOK * DM * 2);
    f16* Qhi = (f16*)take(NTOK * DM * 2);
    f16* Qlo = (f16*)take(NTOK * DM * 2);
    f16* Khi = (f16*)take(NTOK * DM * 2);
    f16* Klo = (f16*)take(NTOK * DM * 2);
    f16* Vhb = (f16*)take(NTOK * DM * 2);

    dim3 tg(16, 16);
    k_wt<<<tg, 256, 0, stream>>>(Wq, Wqt);
    k_wt<<<tg, 256, 0, stream>>>(Wk, Wkt);
    k_wt<<<tg, 256, 0, stream>>>(Wv, Wvt);
    k_wt<<<tg, 256, 0, stream>>>(Wo, Wot);
    k_mask<<<2304, 256, 0, stream>>>(pc, mw1, mb1, mw2, mb2, maskb);

    dim3 gg(96, 8);
    k_cvt<<<6144, 256, 0, stream>>>(query, buf1);
    k_gemm<1><<<gg, 256, 0, stream>>>(buf1, Wqt, bq, Qhi, Qlo);
    k_cvt<<<6144, 256, 0, stream>>>(key, buf1);
    k_gemm<1><<<gg, 256, 0, stream>>>(buf1, Wkt, bk, Khi, Klo);
    k_cvt<<<6144, 256, 0, stream>>>(value, buf1);
    k_gemm<0><<<gg, 256, 0, stream>>>(buf1, Wvt, bv, Vhb, nullptr);

    dim3 ag(12, 256);
    k_attn<<<ag, 256, 0, stream>>>(Qhi, Qlo, Khi, Klo, Vhb, maskb, buf1);

    k_gemm<2><<<gg, 256, 0, stream>>>(buf1, Wot, bo, d_out, nullptr);
}